// Round 4
// baseline (1766.834 us; speedup 1.0000x reference)
//
#include <hip/hip_runtime.h>
#include <float.h>

typedef _Float16 half8 __attribute__((ext_vector_type(8)));
typedef _Float16 half4v __attribute__((ext_vector_type(4)));
typedef float f32x4 __attribute__((ext_vector_type(4)));

#define M_TOTAL 16384
#define N_CODES 8192
#define KDIM    256
#define BM 128
#define BN 128
#define NB (N_CODES / BN)   // 64 partials per query
#define TS 32               // LDS tile k-stride in halfs (m97-style, 16B-aligned)
#define MARGIN 2.5e-3f
// scales keep fp16 values well inside normal range (no subnormal flush)
#define SQ_SCALE 512.0f
#define SE_SCALE 2048.0f
#define INV_PROD 1.9073486328125e-06f   // 2/(512*2048) = 2^-19, exact

// ---------------------------------------------------------------------------
// numpy-bit-exact fp32 pairwise sum of squares over 256 elements (verified r2)
// ---------------------------------------------------------------------------
__device__ __forceinline__ float np_pairwise_sumsq256(const float* __restrict__ p) {
    #pragma clang fp contract(off)
    float tot0, tot1;
    #pragma unroll
    for (int b = 0; b < 2; b++) {
        const float* a = p + b * 128;
        float r[8];
        #pragma unroll
        for (int j = 0; j < 8; j++) { const float v = a[j]; r[j] = v * v; }
        for (int i = 8; i < 128; i += 8) {
            #pragma unroll
            for (int j = 0; j < 8; j++) { const float v = a[i + j]; r[j] += v * v; }
        }
        const float res = ((r[0] + r[1]) + (r[2] + r[3])) + ((r[4] + r[5]) + (r[6] + r[7]));
        if (b == 0) tot0 = res; else tot1 = res;
    }
    return tot0 + tot1;
}

__global__ void esq_kernel(const float* __restrict__ emb, float* __restrict__ esq) {
    const int n = blockIdx.x * blockDim.x + threadIdx.x;
    if (n < N_CODES) esq[n] = np_pairwise_sumsq256(emb + (size_t)n * KDIM);
}
__global__ void qsq_kernel(const float* __restrict__ Q, float* __restrict__ qsq) {
    const int m = blockIdx.x * blockDim.x + threadIdx.x;
    if (m < M_TOTAL) qsq[m] = np_pairwise_sumsq256(Q + (size_t)m * KDIM);
}

// fp32 -> fp16 with power-of-2 scale (exact scaling)
__global__ void conv_kernel(const float* __restrict__ src, _Float16* __restrict__ dst,
                            float scale, int n4) {
    const int i = blockIdx.x * 256 + threadIdx.x;
    if (i >= n4) return;
    const float4 v = ((const float4*)src)[i];
    const half4v h = {(_Float16)(v.x * scale), (_Float16)(v.y * scale),
                      (_Float16)(v.z * scale), (_Float16)(v.w * scale)};
    ((half4v*)dst)[i] = h;
}

// ---------------------------------------------------------------------------
// MFMA approx-distance + per-block TOP-2 argmin partials.
// Block 256 thr = 4 waves (2x2 of 64x64), tile 128x128, BK=32.
// d_approx = fp32( fp32(q_sq+e_sq) - acc*2^-19 )
// ---------------------------------------------------------------------------
union SMemU {
    _Float16 t[2][BM * TS];                                      // Q tile, E tile
    struct { float v1[BM][2]; int i1[BM][2]; float v2[BM][2]; } red;
};

__global__ __launch_bounds__(256, 2)
void mfma_top2_kernel(const _Float16* __restrict__ Qh, const _Float16* __restrict__ Eh,
                      const float* __restrict__ qsq, const float* __restrict__ esq,
                      float* __restrict__ wmin, int* __restrict__ widx,
                      float* __restrict__ wmin2) {
    __shared__ SMemU sm;
    const int tid = threadIdx.x;
    const int m0 = blockIdx.x * BM;
    const int n0 = blockIdx.y * BN;
    const int w = tid >> 6, lane = tid & 63;
    const int wm = w >> 1, wn = w & 1;
    const int qd = lane >> 4, c = lane & 15;
    // staging role: waves 0,1 stage Q halves; waves 2,3 stage E halves
    const int which = w >> 1, half = w & 1;
    const _Float16* src = (which == 0) ? (Qh + (size_t)(m0 + half * 64) * KDIM)
                                       : (Eh + (size_t)(n0 + half * 64) * KDIM);
    _Float16* dst = sm.t[which] + half * 64 * TS;

    f32x4 acc[4][4];
    const f32x4 zero = {0.f, 0.f, 0.f, 0.f};
    #pragma unroll
    for (int mt = 0; mt < 4; mt++)
        #pragma unroll
        for (int nt = 0; nt < 4; nt++) acc[mt][nt] = zero;

    for (int k0 = 0; k0 < KDIM; k0 += 32) {
        if (k0) __syncthreads();
        #pragma unroll
        for (int it = 0; it < 4; it++) {
            const int u = it * 64 + lane;
            const int row = u >> 2, col = u & 3;
            const half8 v = *(const half8*)(src + (size_t)row * KDIM + k0 + col * 8);
            *(half8*)(dst + row * TS + col * 8) = v;
        }
        __syncthreads();
        half8 qa[4];
        #pragma unroll
        for (int mt = 0; mt < 4; mt++)
            qa[mt] = *(const half8*)(sm.t[0] + (wm * 64 + mt * 16 + c) * TS + qd * 8);
        #pragma unroll
        for (int nt = 0; nt < 4; nt++) {
            const half8 eh = *(const half8*)(sm.t[1] + (wn * 64 + nt * 16 + c) * TS + qd * 8);
            #pragma unroll
            for (int mt = 0; mt < 4; mt++)
                acc[mt][nt] = __builtin_amdgcn_mfma_f32_16x16x32_f16(qa[mt], eh, acc[mt][nt], 0, 0, 0);
        }
    }

    // ---- epilogue: top-2 tracking ----
    float qs_l[16];
    #pragma unroll
    for (int mt = 0; mt < 4; mt++)
        #pragma unroll
        for (int r = 0; r < 4; r++)
            qs_l[mt * 4 + r] = qsq[m0 + wm * 64 + mt * 16 + qd * 4 + r];
    float es_l[4];
    #pragma unroll
    for (int nt = 0; nt < 4; nt++) es_l[nt] = esq[n0 + wn * 64 + nt * 16 + c];

    float v1[16], v2[16]; int i1[16];
    #pragma unroll
    for (int i = 0; i < 16; i++) { v1[i] = FLT_MAX; v2[i] = FLT_MAX; i1[i] = 0x7fffffff; }

    #pragma unroll
    for (int mt = 0; mt < 4; mt++)
        #pragma unroll
        for (int nt = 0; nt < 4; nt++)
            #pragma unroll
            for (int r = 0; r < 4; r++) {
                const int i = mt * 4 + r;
                const int n = n0 + wn * 64 + nt * 16 + c;
                float d;
                {
                    #pragma clang fp contract(off)
                    const float t1 = qs_l[i] + es_l[nt];
                    d = t1 - acc[mt][nt][r] * INV_PROD;
                }
                if (d < v1[i] || (d == v1[i] && n < i1[i])) { v2[i] = v1[i]; v1[i] = d; i1[i] = n; }
                else v2[i] = fminf(v2[i], d);
            }
    // butterfly over the 16 column-lanes (same qd group)
    #pragma unroll
    for (int s = 1; s < 16; s <<= 1) {
        #pragma unroll
        for (int i = 0; i < 16; i++) {
            const float ov1 = __shfl_xor(v1[i], s, 64);
            const int   oi1 = __shfl_xor(i1[i], s, 64);
            const float ov2 = __shfl_xor(v2[i], s, 64);
            if (ov1 < v1[i] || (ov1 == v1[i] && oi1 < i1[i])) {
                v2[i] = fminf(v1[i], ov2); v1[i] = ov1; i1[i] = oi1;
            } else v2[i] = fminf(v2[i], ov1);
        }
    }
    __syncthreads();   // staging LDS reads retired; reuse as reduction scratch
    if (c == 0) {
        #pragma unroll
        for (int mt = 0; mt < 4; mt++)
            #pragma unroll
            for (int r = 0; r < 4; r++) {
                const int ml = wm * 64 + mt * 16 + qd * 4 + r;
                sm.red.v1[ml][wn] = v1[mt * 4 + r];
                sm.red.i1[ml][wn] = i1[mt * 4 + r];
                sm.red.v2[ml][wn] = v2[mt * 4 + r];
            }
    }
    __syncthreads();
    if (tid < BM) {
        float a1 = sm.red.v1[tid][0]; int ai = sm.red.i1[tid][0]; float a2 = sm.red.v2[tid][0];
        const float b1 = sm.red.v1[tid][1]; const int bi = sm.red.i1[tid][1];
        const float b2 = sm.red.v2[tid][1];
        if (b1 < a1 || (b1 == a1 && bi < ai)) { a2 = fminf(a1, b2); a1 = b1; ai = bi; }
        else a2 = fminf(a2, b1);
        const size_t o = (size_t)(m0 + tid) * NB + blockIdx.y;
        wmin[o] = a1; widx[o] = ai; wmin2[o] = a2;
    }
}

// ---------------------------------------------------------------------------
// Merge 64 partials/query. Safe gap -> emit winner + gather + loss.
// Narrow gap -> flag for exact refinement.
// ---------------------------------------------------------------------------
__global__ void finalize_kernel(const float* __restrict__ Q, const float* __restrict__ E,
                                const float* __restrict__ wmin, const int* __restrict__ widx,
                                const float* __restrict__ wmin2, int* __restrict__ qflag,
                                float* __restrict__ out) {
    const int q = blockIdx.x;
    const int lane = threadIdx.x;
    float v1 = wmin[(size_t)q * NB + lane];
    int   i1 = widx[(size_t)q * NB + lane];
    float v2 = wmin2[(size_t)q * NB + lane];
    #pragma unroll
    for (int s = 1; s < 64; s <<= 1) {
        const float ov1 = __shfl_xor(v1, s, 64);
        const int   oi1 = __shfl_xor(i1, s, 64);
        const float ov2 = __shfl_xor(v2, s, 64);
        if (ov1 < v1 || (ov1 == v1 && oi1 < i1)) { v2 = fminf(v1, ov2); v1 = ov1; i1 = oi1; }
        else v2 = fminf(v2, ov1);
    }
    const bool flagged = (v2 - v1) < MARGIN;
    if (lane == 0) qflag[q] = flagged ? 1 : 0;
    if (flagged) return;   // deferred to refine_kernel

    if (lane == 0) out[q] = (float)i1;
    const float4 qv = *(const float4*)(Q + (size_t)q * KDIM + lane * 4);
    const float4 ev = *(const float4*)(E + (size_t)i1 * KDIM + lane * 4);
    float4 st;
    {
        #pragma clang fp contract(off)
        st.x = qv.x + (ev.x - qv.x);
        st.y = qv.y + (ev.y - qv.y);
        st.z = qv.z + (ev.z - qv.z);
        st.w = qv.w + (ev.w - qv.w);
    }
    *(float4*)(out + M_TOTAL + (size_t)q * KDIM + lane * 4) = st;

    const float dx = qv.x - ev.x, dy = qv.y - ev.y, dz = qv.z - ev.z, dw = qv.w - ev.w;
    float s = dx * dx + dy * dy + dz * dz + dw * dw;
    #pragma unroll
    for (int off = 32; off > 0; off >>= 1) s += __shfl_down(s, off);
    if (lane == 0)
        atomicAdd(out + M_TOTAL + (size_t)M_TOTAL * KDIM,
                  s * (1.25f / (float)((size_t)M_TOTAL * KDIM)));
}

// ---------------------------------------------------------------------------
// Exact rescore (round-2 fp32 pipeline, verified absmax 0) for flagged queries.
// ---------------------------------------------------------------------------
__global__ void refine_kernel(const float* __restrict__ Q, const float* __restrict__ E,
                              const float* __restrict__ qsq, const float* __restrict__ esq,
                              const int* __restrict__ qflag, float* __restrict__ out) {
    const int q = blockIdx.x;
    if (qflag[q] == 0) return;
    const int tid = threadIdx.x;
    __shared__ float qs[KDIM];
    __shared__ float vred[256];
    __shared__ int   ired[256];
    qs[tid] = Q[(size_t)q * KDIM + tid];
    __syncthreads();
    const float qsv = qsq[q];
    float best = FLT_MAX; int bidx = 0x7fffffff;
    for (int n = tid; n < N_CODES; n += 256) {
        const float* e = E + (size_t)n * KDIM;
        float acc = 0.f;
        for (int k = 0; k < KDIM; k += 4) {       // sequential-k FMA, round-2 order
            const float4 ev = *(const float4*)(e + k);
            acc = fmaf(qs[k + 0], ev.x, acc);
            acc = fmaf(qs[k + 1], ev.y, acc);
            acc = fmaf(qs[k + 2], ev.z, acc);
            acc = fmaf(qs[k + 3], ev.w, acc);
        }
        float d;
        {
            #pragma clang fp contract(off)
            const float t1 = qsv + esq[n];
            d = t1 - 2.0f * acc;
        }
        if (d < best || (d == best && n < bidx)) { best = d; bidx = n; }
    }
    vred[tid] = best; ired[tid] = bidx;
    __syncthreads();
    for (int s = 128; s > 0; s >>= 1) {
        if (tid < s) {
            const float ov = vred[tid + s]; const int oi = ired[tid + s];
            if (ov < vred[tid] || (ov == vred[tid] && oi < ired[tid])) {
                vred[tid] = ov; ired[tid] = oi;
            }
        }
        __syncthreads();
    }
    const int win = ired[0];
    if (tid == 0) out[q] = (float)win;
    if (tid < 64) {
        const int lane = tid;
        const float4 qv = *(const float4*)(Q + (size_t)q * KDIM + lane * 4);
        const float4 ev = *(const float4*)(E + (size_t)win * KDIM + lane * 4);
        float4 st;
        {
            #pragma clang fp contract(off)
            st.x = qv.x + (ev.x - qv.x);
            st.y = qv.y + (ev.y - qv.y);
            st.z = qv.z + (ev.z - qv.z);
            st.w = qv.w + (ev.w - qv.w);
        }
        *(float4*)(out + M_TOTAL + (size_t)q * KDIM + lane * 4) = st;
        const float dx = qv.x - ev.x, dy = qv.y - ev.y, dz = qv.z - ev.z, dw = qv.w - ev.w;
        float s = dx * dx + dy * dy + dz * dz + dw * dw;
        #pragma unroll
        for (int off = 32; off > 0; off >>= 1) s += __shfl_down(s, off);
        if (lane == 0)
            atomicAdd(out + M_TOTAL + (size_t)M_TOTAL * KDIM,
                      s * (1.25f / (float)((size_t)M_TOTAL * KDIM)));
    }
}

extern "C" void kernel_launch(void* const* d_in, const int* in_sizes, int n_in,
                              void* d_out, int out_size, void* d_ws, size_t ws_size,
                              hipStream_t stream) {
    const float* Q = (const float*)d_in[0];   // [16,1024,256] fp32
    const float* E = (const float*)d_in[1];   // [8192,256] fp32
    float* out = (float*)d_out;               // [16384 idx][4194304 quantized][1 loss]

    char* ws = (char*)d_ws;
    _Float16* Qh  = (_Float16*)(ws);                                 // 8 MB
    _Float16* Eh  = (_Float16*)(ws + (size_t)8  * 1024 * 1024);      // 4 MB
    float* qsq    = (float*)   (ws + (size_t)12 * 1024 * 1024);      // 64 KB
    float* esq    = qsq + M_TOTAL;                                   // 32 KB
    float* wmin   = (float*)   (ws + (size_t)13 * 1024 * 1024);      // 4 MB
    int*   widx   = (int*)     (ws + (size_t)17 * 1024 * 1024);      // 4 MB
    float* wmin2  = (float*)   (ws + (size_t)21 * 1024 * 1024);      // 4 MB
    int*   qflag  = (int*)     (ws + (size_t)25 * 1024 * 1024);      // 64 KB

    hipMemsetAsync(out + M_TOTAL + (size_t)M_TOTAL * KDIM, 0, sizeof(float), stream);

    conv_kernel<<<(M_TOTAL * KDIM / 4 + 255) / 256, 256, 0, stream>>>(Q, Qh, SQ_SCALE, M_TOTAL * KDIM / 4);
    conv_kernel<<<(N_CODES * KDIM / 4 + 255) / 256, 256, 0, stream>>>(E, Eh, SE_SCALE, N_CODES * KDIM / 4);
    esq_kernel<<<(N_CODES + 255) / 256, 256, 0, stream>>>(E, esq);
    qsq_kernel<<<(M_TOTAL + 255) / 256, 256, 0, stream>>>(Q, qsq);

    mfma_top2_kernel<<<dim3(M_TOTAL / BM, N_CODES / BN), 256, 0, stream>>>(
        Qh, Eh, qsq, esq, wmin, widx, wmin2);

    finalize_kernel<<<M_TOTAL, 64, 0, stream>>>(Q, E, wmin, widx, wmin2, qflag, out);
    refine_kernel<<<M_TOTAL, 256, 0, stream>>>(Q, E, qsq, esq, qflag, out);
}

// Round 5
// 1196.968 us; speedup vs baseline: 1.4761x; 1.4761x over previous
//
#include <hip/hip_runtime.h>
#include <float.h>

typedef _Float16 half8 __attribute__((ext_vector_type(8)));
typedef _Float16 half4v __attribute__((ext_vector_type(4)));
typedef float f32x4 __attribute__((ext_vector_type(4)));

#define M_TOTAL 16384
#define N_CODES 8192
#define KDIM    256
#define BM 128
#define BN 128
#define NB (N_CODES / BN)   // 64 partials per query
#define TS 32               // LDS tile k-stride in halfs
#define MARGIN 2.5e-3f
#define SQ_SCALE 512.0f
#define SE_SCALE 2048.0f
#define INV_PROD 1.9073486328125e-06f   // 2/(512*2048) = 2^-19, exact
#define REFINE_BLOCKS 1024

// ---------------------------------------------------------------------------
// numpy-bit-exact fp32 pairwise sum of squares over 256 elements (verified r2)
// ---------------------------------------------------------------------------
__device__ __forceinline__ float np_pairwise_sumsq256(const float* __restrict__ p) {
    #pragma clang fp contract(off)
    float tot0, tot1;
    #pragma unroll
    for (int b = 0; b < 2; b++) {
        const float* a = p + b * 128;
        float r[8];
        #pragma unroll
        for (int j = 0; j < 8; j++) { const float v = a[j]; r[j] = v * v; }
        for (int i = 8; i < 128; i += 8) {
            #pragma unroll
            for (int j = 0; j < 8; j++) { const float v = a[i + j]; r[j] += v * v; }
        }
        const float res = ((r[0] + r[1]) + (r[2] + r[3])) + ((r[4] + r[5]) + (r[6] + r[7]));
        if (b == 0) tot0 = res; else tot1 = res;
    }
    return tot0 + tot1;
}

__global__ void esq_kernel(const float* __restrict__ emb, float* __restrict__ esq) {
    const int n = blockIdx.x * blockDim.x + threadIdx.x;
    if (n < N_CODES) esq[n] = np_pairwise_sumsq256(emb + (size_t)n * KDIM);
}
__global__ void qsq_kernel(const float* __restrict__ Q, float* __restrict__ qsq) {
    const int m = blockIdx.x * blockDim.x + threadIdx.x;
    if (m < M_TOTAL) qsq[m] = np_pairwise_sumsq256(Q + (size_t)m * KDIM);
}

// fp32 -> fp16 with power-of-2 scale (exact scaling)
__global__ void conv_kernel(const float* __restrict__ src, _Float16* __restrict__ dst,
                            float scale, int n4) {
    const int i = blockIdx.x * 256 + threadIdx.x;
    if (i >= n4) return;
    const float4 v = ((const float4*)src)[i];
    const half4v h = {(_Float16)(v.x * scale), (_Float16)(v.y * scale),
                      (_Float16)(v.z * scale), (_Float16)(v.w * scale)};
    ((half4v*)dst)[i] = h;
}

// ---------------------------------------------------------------------------
// MFMA approx-distance + per-block TOP-2 argmin partials (unchanged from r4).
// ---------------------------------------------------------------------------
union SMemU {
    _Float16 t[2][BM * TS];
    struct { float v1[BM][2]; int i1[BM][2]; float v2[BM][2]; } red;
};

__global__ __launch_bounds__(256, 2)
void mfma_top2_kernel(const _Float16* __restrict__ Qh, const _Float16* __restrict__ Eh,
                      const float* __restrict__ qsq, const float* __restrict__ esq,
                      float* __restrict__ wmin, int* __restrict__ widx,
                      float* __restrict__ wmin2) {
    __shared__ SMemU sm;
    const int tid = threadIdx.x;
    const int m0 = blockIdx.x * BM;
    const int n0 = blockIdx.y * BN;
    const int w = tid >> 6, lane = tid & 63;
    const int wm = w >> 1, wn = w & 1;
    const int qd = lane >> 4, c = lane & 15;
    const int which = w >> 1, half = w & 1;
    const _Float16* src = (which == 0) ? (Qh + (size_t)(m0 + half * 64) * KDIM)
                                       : (Eh + (size_t)(n0 + half * 64) * KDIM);
    _Float16* dst = sm.t[which] + half * 64 * TS;

    f32x4 acc[4][4];
    const f32x4 zero = {0.f, 0.f, 0.f, 0.f};
    #pragma unroll
    for (int mt = 0; mt < 4; mt++)
        #pragma unroll
        for (int nt = 0; nt < 4; nt++) acc[mt][nt] = zero;

    for (int k0 = 0; k0 < KDIM; k0 += 32) {
        if (k0) __syncthreads();
        #pragma unroll
        for (int it = 0; it < 4; it++) {
            const int u = it * 64 + lane;
            const int row = u >> 2, col = u & 3;
            const half8 v = *(const half8*)(src + (size_t)row * KDIM + k0 + col * 8);
            *(half8*)(dst + row * TS + col * 8) = v;
        }
        __syncthreads();
        half8 qa[4];
        #pragma unroll
        for (int mt = 0; mt < 4; mt++)
            qa[mt] = *(const half8*)(sm.t[0] + (wm * 64 + mt * 16 + c) * TS + qd * 8);
        #pragma unroll
        for (int nt = 0; nt < 4; nt++) {
            const half8 eh = *(const half8*)(sm.t[1] + (wn * 64 + nt * 16 + c) * TS + qd * 8);
            #pragma unroll
            for (int mt = 0; mt < 4; mt++)
                acc[mt][nt] = __builtin_amdgcn_mfma_f32_16x16x32_f16(qa[mt], eh, acc[mt][nt], 0, 0, 0);
        }
    }

    float qs_l[16];
    #pragma unroll
    for (int mt = 0; mt < 4; mt++)
        #pragma unroll
        for (int r = 0; r < 4; r++)
            qs_l[mt * 4 + r] = qsq[m0 + wm * 64 + mt * 16 + qd * 4 + r];
    float es_l[4];
    #pragma unroll
    for (int nt = 0; nt < 4; nt++) es_l[nt] = esq[n0 + wn * 64 + nt * 16 + c];

    float v1[16], v2[16]; int i1[16];
    #pragma unroll
    for (int i = 0; i < 16; i++) { v1[i] = FLT_MAX; v2[i] = FLT_MAX; i1[i] = 0x7fffffff; }

    #pragma unroll
    for (int mt = 0; mt < 4; mt++)
        #pragma unroll
        for (int nt = 0; nt < 4; nt++)
            #pragma unroll
            for (int r = 0; r < 4; r++) {
                const int i = mt * 4 + r;
                const int n = n0 + wn * 64 + nt * 16 + c;
                float d;
                {
                    #pragma clang fp contract(off)
                    const float t1 = qs_l[i] + es_l[nt];
                    d = t1 - acc[mt][nt][r] * INV_PROD;
                }
                if (d < v1[i] || (d == v1[i] && n < i1[i])) { v2[i] = v1[i]; v1[i] = d; i1[i] = n; }
                else v2[i] = fminf(v2[i], d);
            }
    #pragma unroll
    for (int s = 1; s < 16; s <<= 1) {
        #pragma unroll
        for (int i = 0; i < 16; i++) {
            const float ov1 = __shfl_xor(v1[i], s, 64);
            const int   oi1 = __shfl_xor(i1[i], s, 64);
            const float ov2 = __shfl_xor(v2[i], s, 64);
            if (ov1 < v1[i] || (ov1 == v1[i] && oi1 < i1[i])) {
                v2[i] = fminf(v1[i], ov2); v1[i] = ov1; i1[i] = oi1;
            } else v2[i] = fminf(v2[i], ov1);
        }
    }
    __syncthreads();
    if (c == 0) {
        #pragma unroll
        for (int mt = 0; mt < 4; mt++)
            #pragma unroll
            for (int r = 0; r < 4; r++) {
                const int ml = wm * 64 + mt * 16 + qd * 4 + r;
                sm.red.v1[ml][wn] = v1[mt * 4 + r];
                sm.red.i1[ml][wn] = i1[mt * 4 + r];
                sm.red.v2[ml][wn] = v2[mt * 4 + r];
            }
    }
    __syncthreads();
    if (tid < BM) {
        float a1 = sm.red.v1[tid][0]; int ai = sm.red.i1[tid][0]; float a2 = sm.red.v2[tid][0];
        const float b1 = sm.red.v1[tid][1]; const int bi = sm.red.i1[tid][1];
        const float b2 = sm.red.v2[tid][1];
        if (b1 < a1 || (b1 == a1 && bi < ai)) { a2 = fminf(a1, b2); a1 = b1; ai = bi; }
        else a2 = fminf(a2, b1);
        const size_t o = (size_t)(m0 + tid) * NB + blockIdx.y;
        wmin[o] = a1; widx[o] = ai; wmin2[o] = a2;
    }
}

// ---------------------------------------------------------------------------
// Merge 64 partials/query. Safe gap -> emit winner + gather + loss.
// Narrow gap -> append to flagged list (compacted for refine_kernel).
// ---------------------------------------------------------------------------
__global__ void finalize_kernel(const float* __restrict__ Q, const float* __restrict__ E,
                                const float* __restrict__ wmin, const int* __restrict__ widx,
                                const float* __restrict__ wmin2,
                                int* __restrict__ fcount, int* __restrict__ flist,
                                float* __restrict__ out) {
    const int q = blockIdx.x;
    const int lane = threadIdx.x;
    float v1 = wmin[(size_t)q * NB + lane];
    int   i1 = widx[(size_t)q * NB + lane];
    float v2 = wmin2[(size_t)q * NB + lane];
    #pragma unroll
    for (int s = 1; s < 64; s <<= 1) {
        const float ov1 = __shfl_xor(v1, s, 64);
        const int   oi1 = __shfl_xor(i1, s, 64);
        const float ov2 = __shfl_xor(v2, s, 64);
        if (ov1 < v1 || (ov1 == v1 && oi1 < i1)) { v2 = fminf(v1, ov2); v1 = ov1; i1 = oi1; }
        else v2 = fminf(v2, ov1);
    }
    if ((v2 - v1) < MARGIN) {
        if (lane == 0) flist[atomicAdd(fcount, 1)] = q;
        return;   // exact path will produce this query's outputs
    }

    if (lane == 0) out[q] = (float)i1;
    const float4 qv = *(const float4*)(Q + (size_t)q * KDIM + lane * 4);
    const float4 ev = *(const float4*)(E + (size_t)i1 * KDIM + lane * 4);
    float4 st;
    {
        #pragma clang fp contract(off)
        st.x = qv.x + (ev.x - qv.x);
        st.y = qv.y + (ev.y - qv.y);
        st.z = qv.z + (ev.z - qv.z);
        st.w = qv.w + (ev.w - qv.w);
    }
    *(float4*)(out + M_TOTAL + (size_t)q * KDIM + lane * 4) = st;

    const float dx = qv.x - ev.x, dy = qv.y - ev.y, dz = qv.z - ev.z, dw = qv.w - ev.w;
    float s = dx * dx + dy * dy + dz * dz + dw * dw;
    #pragma unroll
    for (int off = 32; off > 0; off >>= 1) s += __shfl_down(s, off);
    if (lane == 0)
        atomicAdd(out + M_TOTAL + (size_t)M_TOTAL * KDIM,
                  s * (1.25f / (float)((size_t)M_TOTAL * KDIM)));
}

// ---------------------------------------------------------------------------
// Refine v2: exact fp32 rescore for flagged queries, wave-per-code cooperative.
// Fixed grid; grid-strides over the compacted flagged list. Per code: 64-lane
// coalesced float4 load of the embedding row, 4 FMAs/lane, butterfly reduce.
// ---------------------------------------------------------------------------
__global__ __launch_bounds__(256, 4)
void refine_kernel(const float* __restrict__ Q, const float* __restrict__ E,
                   const float* __restrict__ qsq, const float* __restrict__ esq,
                   const int* __restrict__ fcount, const int* __restrict__ flist,
                   float* __restrict__ out) {
    const int cnt = *fcount;
    const int tid = threadIdx.x;
    const int w = tid >> 6, lane = tid & 63;
    __shared__ float qs[KDIM];
    __shared__ float wv[4];
    __shared__ int   wi[4];

    for (int fi = blockIdx.x; fi < cnt; fi += REFINE_BLOCKS) {
        const int q = flist[fi];
        __syncthreads();   // protect qs from previous iteration's readers
        qs[tid] = Q[(size_t)q * KDIM + tid];
        __syncthreads();
        const float qsv = qsq[q];
        const float4 qv4 = *(const float4*)(qs + lane * 4);

        float best = FLT_MAX; int bidx = 0x7fffffff;
        for (int i = 0; i < N_CODES / 4; i++) {
            const int n = i * 4 + w;
            const float4 ev = *(const float4*)(E + (size_t)n * KDIM + lane * 4);
            float p = qv4.x * ev.x;
            p = fmaf(qv4.y, ev.y, p);
            p = fmaf(qv4.z, ev.z, p);
            p = fmaf(qv4.w, ev.w, p);
            #pragma unroll
            for (int s = 1; s < 64; s <<= 1) p += __shfl_xor(p, s, 64);
            float d;
            {
                #pragma clang fp contract(off)
                const float t1 = qsv + esq[n];
                d = t1 - 2.0f * p;
            }
            if (d < best) { best = d; bidx = n; }   // ascending n: first occurrence wins
        }
        if (lane == 0) { wv[w] = best; wi[w] = bidx; }
        __syncthreads();
        float bv = wv[0]; int bi = wi[0];
        #pragma unroll
        for (int t = 1; t < 4; t++) {
            const float ov = wv[t]; const int oi = wi[t];
            if (ov < bv || (ov == bv && oi < bi)) { bv = ov; bi = oi; }
        }
        if (tid == 0) out[q] = (float)bi;
        if (tid < 64) {
            const float4 qv = *(const float4*)(Q + (size_t)q * KDIM + lane * 4);
            const float4 ev = *(const float4*)(E + (size_t)bi * KDIM + lane * 4);
            float4 st;
            {
                #pragma clang fp contract(off)
                st.x = qv.x + (ev.x - qv.x);
                st.y = qv.y + (ev.y - qv.y);
                st.z = qv.z + (ev.z - qv.z);
                st.w = qv.w + (ev.w - qv.w);
            }
            *(float4*)(out + M_TOTAL + (size_t)q * KDIM + lane * 4) = st;
            const float dx = qv.x - ev.x, dy = qv.y - ev.y, dz = qv.z - ev.z, dw = qv.w - ev.w;
            float s = dx * dx + dy * dy + dz * dz + dw * dw;
            #pragma unroll
            for (int off = 32; off > 0; off >>= 1) s += __shfl_down(s, off);
            if (lane == 0)
                atomicAdd(out + M_TOTAL + (size_t)M_TOTAL * KDIM,
                          s * (1.25f / (float)((size_t)M_TOTAL * KDIM)));
        }
    }
}

extern "C" void kernel_launch(void* const* d_in, const int* in_sizes, int n_in,
                              void* d_out, int out_size, void* d_ws, size_t ws_size,
                              hipStream_t stream) {
    const float* Q = (const float*)d_in[0];   // [16,1024,256] fp32
    const float* E = (const float*)d_in[1];   // [8192,256] fp32
    float* out = (float*)d_out;               // [16384 idx][4194304 quantized][1 loss]

    char* ws = (char*)d_ws;
    _Float16* Qh  = (_Float16*)(ws);                                 // 8 MB
    _Float16* Eh  = (_Float16*)(ws + (size_t)8  * 1024 * 1024);      // 4 MB
    float* qsq    = (float*)   (ws + (size_t)12 * 1024 * 1024);      // 64 KB
    float* esq    = qsq + M_TOTAL;                                   // 32 KB
    float* wmin   = (float*)   (ws + (size_t)13 * 1024 * 1024);      // 4 MB
    int*   widx   = (int*)     (ws + (size_t)17 * 1024 * 1024);      // 4 MB
    float* wmin2  = (float*)   (ws + (size_t)21 * 1024 * 1024);      // 4 MB
    int*   fcount = (int*)     (ws + (size_t)25 * 1024 * 1024);      // 4 B
    int*   flist  = fcount + 64;                                     // 64 KB

    hipMemsetAsync(out + M_TOTAL + (size_t)M_TOTAL * KDIM, 0, sizeof(float), stream);
    hipMemsetAsync(fcount, 0, sizeof(int), stream);

    conv_kernel<<<(M_TOTAL * KDIM / 4 + 255) / 256, 256, 0, stream>>>(Q, Qh, SQ_SCALE, M_TOTAL * KDIM / 4);
    conv_kernel<<<(N_CODES * KDIM / 4 + 255) / 256, 256, 0, stream>>>(E, Eh, SE_SCALE, N_CODES * KDIM / 4);
    esq_kernel<<<(N_CODES + 255) / 256, 256, 0, stream>>>(E, esq);
    qsq_kernel<<<(M_TOTAL + 255) / 256, 256, 0, stream>>>(Q, qsq);

    mfma_top2_kernel<<<dim3(M_TOTAL / BM, N_CODES / BN), 256, 0, stream>>>(
        Qh, Eh, qsq, esq, wmin, widx, wmin2);

    finalize_kernel<<<M_TOTAL, 64, 0, stream>>>(Q, E, wmin, widx, wmin2, fcount, flist, out);
    refine_kernel<<<REFINE_BLOCKS, 256, 0, stream>>>(Q, E, qsq, esq, fcount, flist, out);
}

// Round 6
// 882.006 us; speedup vs baseline: 2.0032x; 1.3571x over previous
//
#include <hip/hip_runtime.h>
#include <float.h>

typedef _Float16 half8 __attribute__((ext_vector_type(8)));
typedef _Float16 half4v __attribute__((ext_vector_type(4)));
typedef float f32x4 __attribute__((ext_vector_type(4)));

#define M_TOTAL 16384
#define N_CODES 8192
#define KDIM    256
#define BM 128
#define BN 128
#define NB (N_CODES / BN)   // 64 partials per query
#define TS 32               // LDS tile k-stride in halfs
#define MARGIN 2.5e-3f
#define SQ_SCALE 512.0f
#define SE_SCALE 2048.0f
#define INV_PROD 1.9073486328125e-06f   // 2/(512*2048) = 2^-19, exact
#define RP_CHUNK 128                    // refine: codes per wave-task
#define RP_NCH (N_CODES / RP_CHUNK)     // 64 chunks per flagged query
#define RP_BLOCKS 512                   // refine_partial blocks (x4 waves = 2048 tasks in flight)
#define RM_BLOCKS 256                   // refine_merge blocks

// ---------------------------------------------------------------------------
// numpy-bit-exact sum of squares over 256 elements, wave-parallel version.
// numpy pairwise order: per 128-block, 8 chains r_j = sum_k a[8k+j]^2 (mul
// then add, no fma), combined ((r0+r1)+(r2+r3))+((r4+r5)+(r6+r7)); then
// tot0+tot1. Lanes 0-15 of each 16-lane group hold (block b, chain j);
// shfl_xor tree reproduces the exact add order (fp add is commutative).
// 4 rows per wave, 16 rows per 256-thread block.
// ---------------------------------------------------------------------------
__global__ void sumsq_kernel(const float* __restrict__ src, float* __restrict__ dst,
                             int nrows) {
    const int wave = (blockIdx.x * blockDim.x + threadIdx.x) >> 6;
    const int lane = threadIdx.x & 63;
    const int grp = lane >> 4;          // row within wave (0..3)
    const int sub = lane & 15;          // b*8 + j
    const int row = wave * 4 + grp;
    if (row >= nrows) return;
    const float* p = src + (size_t)row * KDIM + (sub >> 3) * 128 + (sub & 7);
    float r;
    {
        #pragma clang fp contract(off)
        float v = p[0];
        r = v * v;
        #pragma unroll
        for (int k = 1; k < 16; k++) { const float w = p[k * 8]; r = r + w * w; }
    }
    const float t1 = r  + __shfl_xor(r,  1, 64);   // r0+r1 (even lanes canonical order)
    const float t2 = t1 + __shfl_xor(t1, 2, 64);   // (r0+r1)+(r2+r3)
    const float t3 = t2 + __shfl_xor(t2, 4, 64);   // tot_b
    const float t4 = t3 + __shfl_xor(t3, 8, 64);   // tot0+tot1
    if (sub == 0) dst[row] = t4;
}

// fp32 -> fp16 with power-of-2 scale (exact scaling)
__global__ void conv_kernel(const float* __restrict__ src, _Float16* __restrict__ dst,
                            float scale, int n4) {
    const int i = blockIdx.x * 256 + threadIdx.x;
    if (i >= n4) return;
    const float4 v = ((const float4*)src)[i];
    const half4v h = {(_Float16)(v.x * scale), (_Float16)(v.y * scale),
                      (_Float16)(v.z * scale), (_Float16)(v.w * scale)};
    ((half4v*)dst)[i] = h;
}

// ---------------------------------------------------------------------------
// MFMA approx-distance + per-block TOP-2 argmin partials (unchanged from r4/r5;
// will tune next round with its counters).
// ---------------------------------------------------------------------------
union SMemU {
    _Float16 t[2][BM * TS];
    struct { float v1[BM][2]; int i1[BM][2]; float v2[BM][2]; } red;
};

__global__ __launch_bounds__(256, 2)
void mfma_top2_kernel(const _Float16* __restrict__ Qh, const _Float16* __restrict__ Eh,
                      const float* __restrict__ qsq, const float* __restrict__ esq,
                      float* __restrict__ wmin, int* __restrict__ widx,
                      float* __restrict__ wmin2) {
    __shared__ SMemU sm;
    const int tid = threadIdx.x;
    const int m0 = blockIdx.x * BM;
    const int n0 = blockIdx.y * BN;
    const int w = tid >> 6, lane = tid & 63;
    const int wm = w >> 1, wn = w & 1;
    const int qd = lane >> 4, c = lane & 15;
    const int which = w >> 1, half = w & 1;
    const _Float16* src = (which == 0) ? (Qh + (size_t)(m0 + half * 64) * KDIM)
                                       : (Eh + (size_t)(n0 + half * 64) * KDIM);
    _Float16* dst = sm.t[which] + half * 64 * TS;

    f32x4 acc[4][4];
    const f32x4 zero = {0.f, 0.f, 0.f, 0.f};
    #pragma unroll
    for (int mt = 0; mt < 4; mt++)
        #pragma unroll
        for (int nt = 0; nt < 4; nt++) acc[mt][nt] = zero;

    for (int k0 = 0; k0 < KDIM; k0 += 32) {
        if (k0) __syncthreads();
        #pragma unroll
        for (int it = 0; it < 4; it++) {
            const int u = it * 64 + lane;
            const int row = u >> 2, col = u & 3;
            const half8 v = *(const half8*)(src + (size_t)row * KDIM + k0 + col * 8);
            *(half8*)(dst + row * TS + col * 8) = v;
        }
        __syncthreads();
        half8 qa[4];
        #pragma unroll
        for (int mt = 0; mt < 4; mt++)
            qa[mt] = *(const half8*)(sm.t[0] + (wm * 64 + mt * 16 + c) * TS + qd * 8);
        #pragma unroll
        for (int nt = 0; nt < 4; nt++) {
            const half8 eh = *(const half8*)(sm.t[1] + (wn * 64 + nt * 16 + c) * TS + qd * 8);
            #pragma unroll
            for (int mt = 0; mt < 4; mt++)
                acc[mt][nt] = __builtin_amdgcn_mfma_f32_16x16x32_f16(qa[mt], eh, acc[mt][nt], 0, 0, 0);
        }
    }

    float qs_l[16];
    #pragma unroll
    for (int mt = 0; mt < 4; mt++)
        #pragma unroll
        for (int r = 0; r < 4; r++)
            qs_l[mt * 4 + r] = qsq[m0 + wm * 64 + mt * 16 + qd * 4 + r];
    float es_l[4];
    #pragma unroll
    for (int nt = 0; nt < 4; nt++) es_l[nt] = esq[n0 + wn * 64 + nt * 16 + c];

    float v1[16], v2[16]; int i1[16];
    #pragma unroll
    for (int i = 0; i < 16; i++) { v1[i] = FLT_MAX; v2[i] = FLT_MAX; i1[i] = 0x7fffffff; }

    #pragma unroll
    for (int mt = 0; mt < 4; mt++)
        #pragma unroll
        for (int nt = 0; nt < 4; nt++)
            #pragma unroll
            for (int r = 0; r < 4; r++) {
                const int i = mt * 4 + r;
                const int n = n0 + wn * 64 + nt * 16 + c;
                float d;
                {
                    #pragma clang fp contract(off)
                    const float t1 = qs_l[i] + es_l[nt];
                    d = t1 - acc[mt][nt][r] * INV_PROD;
                }
                if (d < v1[i] || (d == v1[i] && n < i1[i])) { v2[i] = v1[i]; v1[i] = d; i1[i] = n; }
                else v2[i] = fminf(v2[i], d);
            }
    #pragma unroll
    for (int s = 1; s < 16; s <<= 1) {
        #pragma unroll
        for (int i = 0; i < 16; i++) {
            const float ov1 = __shfl_xor(v1[i], s, 64);
            const int   oi1 = __shfl_xor(i1[i], s, 64);
            const float ov2 = __shfl_xor(v2[i], s, 64);
            if (ov1 < v1[i] || (ov1 == v1[i] && oi1 < i1[i])) {
                v2[i] = fminf(v1[i], ov2); v1[i] = ov1; i1[i] = oi1;
            } else v2[i] = fminf(v2[i], ov1);
        }
    }
    __syncthreads();
    if (c == 0) {
        #pragma unroll
        for (int mt = 0; mt < 4; mt++)
            #pragma unroll
            for (int r = 0; r < 4; r++) {
                const int ml = wm * 64 + mt * 16 + qd * 4 + r;
                sm.red.v1[ml][wn] = v1[mt * 4 + r];
                sm.red.i1[ml][wn] = i1[mt * 4 + r];
                sm.red.v2[ml][wn] = v2[mt * 4 + r];
            }
    }
    __syncthreads();
    if (tid < BM) {
        float a1 = sm.red.v1[tid][0]; int ai = sm.red.i1[tid][0]; float a2 = sm.red.v2[tid][0];
        const float b1 = sm.red.v1[tid][1]; const int bi = sm.red.i1[tid][1];
        const float b2 = sm.red.v2[tid][1];
        if (b1 < a1 || (b1 == a1 && bi < ai)) { a2 = fminf(a1, b2); a1 = b1; ai = bi; }
        else a2 = fminf(a2, b1);
        const size_t o = (size_t)(m0 + tid) * NB + blockIdx.y;
        wmin[o] = a1; widx[o] = ai; wmin2[o] = a2;
    }
}

// ---------------------------------------------------------------------------
// Merge 64 partials/query. Safe gap -> emit winner + gather + loss.
// Narrow gap -> append to compacted flagged list.
// ---------------------------------------------------------------------------
__global__ void finalize_kernel(const float* __restrict__ Q, const float* __restrict__ E,
                                const float* __restrict__ wmin, const int* __restrict__ widx,
                                const float* __restrict__ wmin2,
                                int* __restrict__ fcount, int* __restrict__ flist,
                                float* __restrict__ out) {
    const int q = blockIdx.x;
    const int lane = threadIdx.x;
    float v1 = wmin[(size_t)q * NB + lane];
    int   i1 = widx[(size_t)q * NB + lane];
    float v2 = wmin2[(size_t)q * NB + lane];
    #pragma unroll
    for (int s = 1; s < 64; s <<= 1) {
        const float ov1 = __shfl_xor(v1, s, 64);
        const int   oi1 = __shfl_xor(i1, s, 64);
        const float ov2 = __shfl_xor(v2, s, 64);
        if (ov1 < v1 || (ov1 == v1 && oi1 < i1)) { v2 = fminf(v1, ov2); v1 = ov1; i1 = oi1; }
        else v2 = fminf(v2, ov1);
    }
    if ((v2 - v1) < MARGIN) {
        if (lane == 0) flist[atomicAdd(fcount, 1)] = q;
        return;   // exact path produces this query's outputs
    }

    if (lane == 0) out[q] = (float)i1;
    const float4 qv = *(const float4*)(Q + (size_t)q * KDIM + lane * 4);
    const float4 ev = *(const float4*)(E + (size_t)i1 * KDIM + lane * 4);
    float4 st;
    {
        #pragma clang fp contract(off)
        st.x = qv.x + (ev.x - qv.x);
        st.y = qv.y + (ev.y - qv.y);
        st.z = qv.z + (ev.z - qv.z);
        st.w = qv.w + (ev.w - qv.w);
    }
    *(float4*)(out + M_TOTAL + (size_t)q * KDIM + lane * 4) = st;

    const float dx = qv.x - ev.x, dy = qv.y - ev.y, dz = qv.z - ev.z, dw = qv.w - ev.w;
    float s = dx * dx + dy * dy + dz * dz + dw * dw;
    #pragma unroll
    for (int off = 32; off > 0; off >>= 1) s += __shfl_down(s, off);
    if (lane == 0)
        atomicAdd(out + M_TOTAL + (size_t)M_TOTAL * KDIM,
                  s * (1.25f / (float)((size_t)M_TOTAL * KDIM)));
}

// ---------------------------------------------------------------------------
// Refine phase 1: wave-level tasks (flagged query, 128-code chunk).
// Each wave: coalesced 1KB row load, 4 FMA/lane, xor-butterfly dot (all lanes
// converge to identical bits; same summation as r5's verified refine),
// two-step-rounded distance, strict-< argmin (ascending n => first occurrence).
// ---------------------------------------------------------------------------
__global__ __launch_bounds__(256, 4)
void refine_partial_kernel(const float* __restrict__ Q, const float* __restrict__ E,
                           const float* __restrict__ qsq, const float* __restrict__ esq,
                           const int* __restrict__ fcount, const int* __restrict__ flist,
                           float* __restrict__ rp_v, int* __restrict__ rp_i) {
    const int cnt = *fcount;
    const int lane = threadIdx.x & 63;
    const int wid = blockIdx.x * 4 + (threadIdx.x >> 6);
    const int nwaves = RP_BLOCKS * 4;
    const int ntasks = cnt * RP_NCH;

    for (int t = wid; t < ntasks; t += nwaves) {
        const int fi = t >> 6;            // flagged-list position
        const int chunk = t & (RP_NCH - 1);
        const int q = flist[fi];
        const float qsv = qsq[q];
        const float4 qv4 = *(const float4*)(Q + (size_t)q * KDIM + lane * 4);
        const int n0 = chunk * RP_CHUNK;

        float best = FLT_MAX; int bidx = 0x7fffffff;
        for (int i = 0; i < RP_CHUNK; i++) {
            const int n = n0 + i;
            const float4 ev = *(const float4*)(E + (size_t)n * KDIM + lane * 4);
            float p = qv4.x * ev.x;
            p = fmaf(qv4.y, ev.y, p);
            p = fmaf(qv4.z, ev.z, p);
            p = fmaf(qv4.w, ev.w, p);
            #pragma unroll
            for (int s = 1; s < 64; s <<= 1) p += __shfl_xor(p, s, 64);
            float d;
            {
                #pragma clang fp contract(off)
                const float t1 = qsv + esq[n];
                d = t1 - 2.0f * p;
            }
            if (d < best) { best = d; bidx = n; }
        }
        if (lane == 0) {
            rp_v[(size_t)fi * RP_NCH + chunk] = best;
            rp_i[(size_t)fi * RP_NCH + chunk] = bidx;
        }
    }
}

// ---------------------------------------------------------------------------
// Refine phase 2: 64-lane lexicographic reduce of the 64 chunk partials per
// flagged query; emit index, gather ST row, accumulate loss.
// ---------------------------------------------------------------------------
__global__ void refine_merge_kernel(const float* __restrict__ Q, const float* __restrict__ E,
                                    const int* __restrict__ fcount, const int* __restrict__ flist,
                                    const float* __restrict__ rp_v, const int* __restrict__ rp_i,
                                    float* __restrict__ out) {
    const int cnt = *fcount;
    const int lane = threadIdx.x;
    for (int fi = blockIdx.x; fi < cnt; fi += RM_BLOCKS) {
        const int q = flist[fi];
        float bv = rp_v[(size_t)fi * RP_NCH + lane];
        int   bi = rp_i[(size_t)fi * RP_NCH + lane];
        #pragma unroll
        for (int s = 1; s < 64; s <<= 1) {
            const float ov = __shfl_xor(bv, s, 64);
            const int   oi = __shfl_xor(bi, s, 64);
            if (ov < bv || (ov == bv && oi < bi)) { bv = ov; bi = oi; }
        }
        if (lane == 0) out[q] = (float)bi;

        const float4 qv = *(const float4*)(Q + (size_t)q * KDIM + lane * 4);
        const float4 ev = *(const float4*)(E + (size_t)bi * KDIM + lane * 4);
        float4 st;
        {
            #pragma clang fp contract(off)
            st.x = qv.x + (ev.x - qv.x);
            st.y = qv.y + (ev.y - qv.y);
            st.z = qv.z + (ev.z - qv.z);
            st.w = qv.w + (ev.w - qv.w);
        }
        *(float4*)(out + M_TOTAL + (size_t)q * KDIM + lane * 4) = st;
        const float dx = qv.x - ev.x, dy = qv.y - ev.y, dz = qv.z - ev.z, dw = qv.w - ev.w;
        float s = dx * dx + dy * dy + dz * dz + dw * dw;
        #pragma unroll
        for (int off = 32; off > 0; off >>= 1) s += __shfl_down(s, off);
        if (lane == 0)
            atomicAdd(out + M_TOTAL + (size_t)M_TOTAL * KDIM,
                      s * (1.25f / (float)((size_t)M_TOTAL * KDIM)));
    }
}

extern "C" void kernel_launch(void* const* d_in, const int* in_sizes, int n_in,
                              void* d_out, int out_size, void* d_ws, size_t ws_size,
                              hipStream_t stream) {
    const float* Q = (const float*)d_in[0];   // [16,1024,256] fp32
    const float* E = (const float*)d_in[1];   // [8192,256] fp32
    float* out = (float*)d_out;               // [16384 idx][4194304 quantized][1 loss]

    char* ws = (char*)d_ws;
    _Float16* Qh  = (_Float16*)(ws);                                 // 0..8 MB
    _Float16* Eh  = (_Float16*)(ws + (size_t)8  * 1024 * 1024);      // 8..12 MB
    float* qsq    = (float*)   (ws + (size_t)12 * 1024 * 1024);      // 64 KB
    float* esq    = qsq + M_TOTAL;                                   // 32 KB
    float* wmin   = (float*)   (ws + (size_t)13 * 1024 * 1024);      // 13..17 MB
    int*   widx   = (int*)     (ws + (size_t)17 * 1024 * 1024);      // 17..21 MB
    float* wmin2  = (float*)   (ws + (size_t)21 * 1024 * 1024);      // 21..25 MB
    int*   fcount = (int*)     (ws + (size_t)25 * 1024 * 1024);      // 4 B
    int*   flist  = fcount + 64;                                     // 64 KB
    // refine partials alias wmin/widx: finalize has consumed them before
    // refine_partial writes (stream-ordered within one launch).
    float* rp_v   = wmin;                                            // 16384*64*4 = 4 MB
    int*   rp_i   = widx;                                            // 4 MB

    hipMemsetAsync(out + M_TOTAL + (size_t)M_TOTAL * KDIM, 0, sizeof(float), stream);
    hipMemsetAsync(fcount, 0, sizeof(int), stream);

    conv_kernel<<<(M_TOTAL * KDIM / 4 + 255) / 256, 256, 0, stream>>>(Q, Qh, SQ_SCALE, M_TOTAL * KDIM / 4);
    conv_kernel<<<(N_CODES * KDIM / 4 + 255) / 256, 256, 0, stream>>>(E, Eh, SE_SCALE, N_CODES * KDIM / 4);
    sumsq_kernel<<<(N_CODES / 16 + 0), 256, 0, stream>>>(E, esq, N_CODES);      // 512 blocks
    sumsq_kernel<<<(M_TOTAL / 16 + 0), 256, 0, stream>>>(Q, qsq, M_TOTAL);      // 1024 blocks

    mfma_top2_kernel<<<dim3(M_TOTAL / BM, N_CODES / BN), 256, 0, stream>>>(
        Qh, Eh, qsq, esq, wmin, widx, wmin2);

    finalize_kernel<<<M_TOTAL, 64, 0, stream>>>(Q, E, wmin, widx, wmin2, fcount, flist, out);
    refine_partial_kernel<<<RP_BLOCKS, 256, 0, stream>>>(Q, E, qsq, esq, fcount, flist, rp_v, rp_i);
    refine_merge_kernel<<<RM_BLOCKS, 64, 0, stream>>>(Q, E, fcount, flist, rp_v, rp_i, out);
}

// Round 7
// 724.862 us; speedup vs baseline: 2.4375x; 1.2168x over previous
//
#include <hip/hip_runtime.h>
#include <float.h>

typedef _Float16 half8 __attribute__((ext_vector_type(8)));
typedef _Float16 half4v __attribute__((ext_vector_type(4)));
typedef float f32x4 __attribute__((ext_vector_type(4)));

#define M_TOTAL 16384
#define N_CODES 8192
#define KDIM    256
#define BM 128
#define BN 128
#define NB (N_CODES / BN)   // 64 partials per query
#define TS 32               // LDS tile k-stride in halfs (swizzled layout)
#define MARGIN 3.0e-3f
#define SQ_SCALE 512.0f
#define SE_SCALE 2048.0f
#define INV_PROD 1.9073486328125e-06f   // 2/(512*2048) = 2^-19, exact
#define RP_CHUNK 128
#define RP_NCH (N_CODES / RP_CHUNK)
#define RP_BLOCKS 512
#define RM_BLOCKS 256

// ---------------------------------------------------------------------------
// Fused prep: fp32 -> fp16 (exact pow2 scale) + numpy-bit-exact sumsq.
// One block = 4 rows. All 256 threads convert (one float4 -> half4 each);
// wave 0 then computes the np-pairwise sumsq (rows are L1-hot).
// np order: per 128-block, 8 chains j combined ((r0+r1)+(r2+r3))+((r4+r5)+
// (r6+r7)); then tot0+tot1. 16 lanes/row = (block b, chain j); shfl_xor tree
// reproduces the exact add order (fp add commutative => bit-exact).
// ---------------------------------------------------------------------------
__global__ void prep_kernel(const float* __restrict__ src, _Float16* __restrict__ dst,
                            float* __restrict__ sq, float scale) {
    const int tid = threadIdx.x;
    const int row0 = blockIdx.x * 4;
    {   // convert
        const int r = row0 + (tid >> 6);
        const int e4 = tid & 63;
        const float4 v = *(const float4*)(src + (size_t)r * KDIM + e4 * 4);
        const half4v h = {(_Float16)(v.x * scale), (_Float16)(v.y * scale),
                          (_Float16)(v.z * scale), (_Float16)(v.w * scale)};
        ((half4v*)(dst + (size_t)r * KDIM))[e4] = h;
    }
    if (tid < 64) {   // np-bit-exact sumsq, 4 rows on wave 0
        const int grp = tid >> 4;       // row in [0,4)
        const int sub = tid & 15;       // b*8 + j
        const int row = row0 + grp;
        const float* p = src + (size_t)row * KDIM + (sub >> 3) * 128 + (sub & 7);
        float r;
        {
            #pragma clang fp contract(off)
            float v = p[0];
            r = v * v;
            #pragma unroll
            for (int k = 1; k < 16; k++) { const float w = p[k * 8]; r = r + w * w; }
        }
        const float t1 = r  + __shfl_xor(r,  1, 64);
        const float t2 = t1 + __shfl_xor(t1, 2, 64);
        const float t3 = t2 + __shfl_xor(t2, 4, 64);
        const float t4 = t3 + __shfl_xor(t3, 8, 64);
        if (sub == 0) sq[row] = t4;
    }
}

// ---------------------------------------------------------------------------
// MFMA approx-distance + packed-u32 top-2 partials.
// LDS XOR swizzle: physical k-column p = qd ^ ((row>>1)&3)  -> fragment reads
// and staging writes are both 2-way banked (free). Comparator key:
//   d = fmaf(acc, -2^-19, e_sq + 8)   (positive => int-monotone)
//   key = (bits(d) & ~127) | local_code_idx(7b)
// q_sq dropped (per-query constant, cancels in ordering and gap).
// ---------------------------------------------------------------------------
union SMemU {
    _Float16 t[2][BM * TS];
    struct { unsigned k1[BM][2]; unsigned k2[BM][2]; } red;
};

__global__ __launch_bounds__(256, 2)
void mfma_top2_kernel(const _Float16* __restrict__ Qh, const _Float16* __restrict__ Eh,
                      const float* __restrict__ esq,
                      unsigned* __restrict__ k1s, unsigned* __restrict__ k2s) {
    __shared__ SMemU sm;
    const int tid = threadIdx.x;
    const int m0 = blockIdx.x * BM;
    const int n0 = blockIdx.y * BN;
    const int w = tid >> 6, lane = tid & 63;
    const int wm = w >> 1, wn = w & 1;
    const int qd = lane >> 4, c = lane & 15;
    const int which = w >> 1, half = w & 1;
    const _Float16* src = (which == 0) ? (Qh + (size_t)(m0 + half * 64) * KDIM)
                                       : (Eh + (size_t)(n0 + half * 64) * KDIM);
    _Float16* dst = sm.t[which] + half * 64 * TS;

    f32x4 acc[4][4];
    const f32x4 zero = {0.f, 0.f, 0.f, 0.f};
    #pragma unroll
    for (int mt = 0; mt < 4; mt++)
        #pragma unroll
        for (int nt = 0; nt < 4; nt++) acc[mt][nt] = zero;

    const int csw = (c >> 1) & 3;   // read-side swizzle term ((abs_row>>1)&3 == (c>>1)&3)

    for (int k0 = 0; k0 < KDIM; k0 += 32) {
        if (k0) __syncthreads();
        #pragma unroll
        for (int it = 0; it < 4; it++) {
            const int u = it * 64 + lane;
            const int row = u >> 2, col = u & 3;
            const half8 v = *(const half8*)(src + (size_t)row * KDIM + k0 + col * 8);
            *(half8*)(dst + row * TS + (col ^ ((row >> 1) & 3)) * 8) = v;
        }
        __syncthreads();
        half8 qa[4];
        #pragma unroll
        for (int mt = 0; mt < 4; mt++)
            qa[mt] = *(const half8*)(sm.t[0] + (wm * 64 + mt * 16 + c) * TS + (qd ^ csw) * 8);
        #pragma unroll
        for (int nt = 0; nt < 4; nt++) {
            const half8 eh = *(const half8*)(sm.t[1] + (wn * 64 + nt * 16 + c) * TS + (qd ^ csw) * 8);
            #pragma unroll
            for (int mt = 0; mt < 4; mt++)
                acc[mt][nt] = __builtin_amdgcn_mfma_f32_16x16x32_f16(qa[mt], eh, acc[mt][nt], 0, 0, 0);
        }
    }

    // ---- epilogue: packed top-2 ----
    float es8[4];
    #pragma unroll
    for (int nt = 0; nt < 4; nt++) es8[nt] = esq[n0 + wn * 64 + nt * 16 + c] + 8.0f;

    unsigned k1[16], k2[16];
    #pragma unroll
    for (int i = 0; i < 16; i++) { k1[i] = 0xFFFFFFFFu; k2[i] = 0xFFFFFFFFu; }

    #pragma unroll
    for (int mt = 0; mt < 4; mt++)
        #pragma unroll
        for (int nt = 0; nt < 4; nt++) {
            const unsigned nl = (unsigned)(wn * 64 + nt * 16 + c);   // local idx [0,128)
            #pragma unroll
            for (int r = 0; r < 4; r++) {
                const int i = mt * 4 + r;
                const float d = fmaf(acc[mt][nt][r], -INV_PROD, es8[nt]);
                const unsigned k = (__float_as_uint(d) & 0xFFFFFF80u) | nl;
                const unsigned t = min(k1[i], k);
                k2[i] = min(k2[i], max(k1[i], k));
                k1[i] = t;
            }
        }
    #pragma unroll
    for (int s = 1; s < 16; s <<= 1) {
        #pragma unroll
        for (int i = 0; i < 16; i++) {
            const unsigned ok1 = (unsigned)__shfl_xor((int)k1[i], s, 64);
            const unsigned ok2 = (unsigned)__shfl_xor((int)k2[i], s, 64);
            const unsigned t = min(k1[i], ok1);
            k2[i] = min(min(k2[i], ok2), max(k1[i], ok1));
            k1[i] = t;
        }
    }
    __syncthreads();   // staging reads retired; reuse LDS for cross-wave merge
    if (c == 0) {
        #pragma unroll
        for (int mt = 0; mt < 4; mt++)
            #pragma unroll
            for (int r = 0; r < 4; r++) {
                const int ml = wm * 64 + mt * 16 + qd * 4 + r;
                sm.red.k1[ml][wn] = k1[mt * 4 + r];
                sm.red.k2[ml][wn] = k2[mt * 4 + r];
            }
    }
    __syncthreads();
    if (tid < BM) {
        const unsigned a1 = sm.red.k1[tid][0], b1 = sm.red.k1[tid][1];
        const unsigned a2 = sm.red.k2[tid][0], b2 = sm.red.k2[tid][1];
        const size_t o = (size_t)(m0 + tid) * NB + blockIdx.y;
        k1s[o] = min(a1, b1);
        k2s[o] = min(min(a2, b2), max(a1, b1));
    }
}

// ---------------------------------------------------------------------------
// Merge 64 packed partials/query (4 queries per 256-thr block, one per wave).
// Safe gap -> emit winner + gather + loss. Narrow gap -> flag.
// ---------------------------------------------------------------------------
__global__ void finalize_kernel(const float* __restrict__ Q, const float* __restrict__ E,
                                const unsigned* __restrict__ k1s, const unsigned* __restrict__ k2s,
                                int* __restrict__ fcount, int* __restrict__ flist,
                                float* __restrict__ out) {
    const int q = blockIdx.x * 4 + (threadIdx.x >> 6);
    const int lane = threadIdx.x & 63;
    const unsigned k1 = k1s[(size_t)q * NB + lane];
    const unsigned k2 = k2s[(size_t)q * NB + lane];
    float v1 = __uint_as_float(k1 & 0xFFFFFF80u);
    int   gi = lane * 128 + (int)(k1 & 127u);
    float v2 = __uint_as_float(k2 & 0xFFFFFF80u);
    #pragma unroll
    for (int s = 1; s < 64; s <<= 1) {
        const float ov1 = __shfl_xor(v1, s, 64);
        const int   ogi = __shfl_xor(gi, s, 64);
        const float ov2 = __shfl_xor(v2, s, 64);
        const float nv2 = fminf(fminf(v2, ov2), fmaxf(v1, ov1));
        const bool take = (ov1 < v1) || (ov1 == v1 && ogi < gi);
        v1 = take ? ov1 : v1;
        gi = take ? ogi : gi;
        v2 = nv2;
    }
    if ((v2 - v1) < MARGIN) {
        if (lane == 0) flist[atomicAdd(fcount, 1)] = q;
        return;   // exact path produces this query's outputs
    }

    if (lane == 0) out[q] = (float)gi;
    const float4 qv = *(const float4*)(Q + (size_t)q * KDIM + lane * 4);
    const float4 ev = *(const float4*)(E + (size_t)gi * KDIM + lane * 4);
    float4 st;
    {
        #pragma clang fp contract(off)
        st.x = qv.x + (ev.x - qv.x);
        st.y = qv.y + (ev.y - qv.y);
        st.z = qv.z + (ev.z - qv.z);
        st.w = qv.w + (ev.w - qv.w);
    }
    *(float4*)(out + M_TOTAL + (size_t)q * KDIM + lane * 4) = st;

    const float dx = qv.x - ev.x, dy = qv.y - ev.y, dz = qv.z - ev.z, dw = qv.w - ev.w;
    float s = dx * dx + dy * dy + dz * dz + dw * dw;
    #pragma unroll
    for (int off = 32; off > 0; off >>= 1) s += __shfl_down(s, off);
    if (lane == 0)
        atomicAdd(out + M_TOTAL + (size_t)M_TOTAL * KDIM,
                  s * (1.25f / (float)((size_t)M_TOTAL * KDIM)));
}

// ---------------------------------------------------------------------------
// Refine phase 1: wave tasks (flagged query, 128-code chunk). Exact fp32
// np-pipeline distances (verified r5/r6), strict-< argmin over ascending n.
// ---------------------------------------------------------------------------
__global__ __launch_bounds__(256, 4)
void refine_partial_kernel(const float* __restrict__ Q, const float* __restrict__ E,
                           const float* __restrict__ qsq, const float* __restrict__ esq,
                           const int* __restrict__ fcount, const int* __restrict__ flist,
                           float* __restrict__ rp_v, int* __restrict__ rp_i) {
    const int cnt = *fcount;
    const int lane = threadIdx.x & 63;
    const int wid = blockIdx.x * 4 + (threadIdx.x >> 6);
    const int nwaves = RP_BLOCKS * 4;
    const int ntasks = cnt * RP_NCH;

    for (int t = wid; t < ntasks; t += nwaves) {
        const int fi = t >> 6;
        const int chunk = t & (RP_NCH - 1);
        const int q = flist[fi];
        const float qsv = qsq[q];
        const float4 qv4 = *(const float4*)(Q + (size_t)q * KDIM + lane * 4);
        const int n0 = chunk * RP_CHUNK;

        float best = FLT_MAX; int bidx = 0x7fffffff;
        for (int i = 0; i < RP_CHUNK; i++) {
            const int n = n0 + i;
            const float4 ev = *(const float4*)(E + (size_t)n * KDIM + lane * 4);
            float p = qv4.x * ev.x;
            p = fmaf(qv4.y, ev.y, p);
            p = fmaf(qv4.z, ev.z, p);
            p = fmaf(qv4.w, ev.w, p);
            #pragma unroll
            for (int s = 1; s < 64; s <<= 1) p += __shfl_xor(p, s, 64);
            float d;
            {
                #pragma clang fp contract(off)
                const float t1 = qsv + esq[n];
                d = t1 - 2.0f * p;
            }
            if (d < best) { best = d; bidx = n; }
        }
        if (lane == 0) {
            rp_v[(size_t)fi * RP_NCH + chunk] = best;
            rp_i[(size_t)fi * RP_NCH + chunk] = bidx;
        }
    }
}

__global__ void refine_merge_kernel(const float* __restrict__ Q, const float* __restrict__ E,
                                    const int* __restrict__ fcount, const int* __restrict__ flist,
                                    const float* __restrict__ rp_v, const int* __restrict__ rp_i,
                                    float* __restrict__ out) {
    const int cnt = *fcount;
    const int lane = threadIdx.x;
    for (int fi = blockIdx.x; fi < cnt; fi += RM_BLOCKS) {
        const int q = flist[fi];
        float bv = rp_v[(size_t)fi * RP_NCH + lane];
        int   bi = rp_i[(size_t)fi * RP_NCH + lane];
        #pragma unroll
        for (int s = 1; s < 64; s <<= 1) {
            const float ov = __shfl_xor(bv, s, 64);
            const int   oi = __shfl_xor(bi, s, 64);
            if (ov < bv || (ov == bv && oi < bi)) { bv = ov; bi = oi; }
        }
        if (lane == 0) out[q] = (float)bi;

        const float4 qv = *(const float4*)(Q + (size_t)q * KDIM + lane * 4);
        const float4 ev = *(const float4*)(E + (size_t)bi * KDIM + lane * 4);
        float4 st;
        {
            #pragma clang fp contract(off)
            st.x = qv.x + (ev.x - qv.x);
            st.y = qv.y + (ev.y - qv.y);
            st.z = qv.z + (ev.z - qv.z);
            st.w = qv.w + (ev.w - qv.w);
        }
        *(float4*)(out + M_TOTAL + (size_t)q * KDIM + lane * 4) = st;
        const float dx = qv.x - ev.x, dy = qv.y - ev.y, dz = qv.z - ev.z, dw = qv.w - ev.w;
        float s = dx * dx + dy * dy + dz * dz + dw * dw;
        #pragma unroll
        for (int off = 32; off > 0; off >>= 1) s += __shfl_down(s, off);
        if (lane == 0)
            atomicAdd(out + M_TOTAL + (size_t)M_TOTAL * KDIM,
                      s * (1.25f / (float)((size_t)M_TOTAL * KDIM)));
    }
}

extern "C" void kernel_launch(void* const* d_in, const int* in_sizes, int n_in,
                              void* d_out, int out_size, void* d_ws, size_t ws_size,
                              hipStream_t stream) {
    const float* Q = (const float*)d_in[0];   // [16,1024,256] fp32
    const float* E = (const float*)d_in[1];   // [8192,256] fp32
    float* out = (float*)d_out;               // [16384 idx][4194304 quantized][1 loss]

    char* ws = (char*)d_ws;
    _Float16* Qh  = (_Float16*)(ws);                                 // 0..8 MB
    _Float16* Eh  = (_Float16*)(ws + (size_t)8  * 1024 * 1024);      // 8..12 MB
    float* qsq    = (float*)   (ws + (size_t)12 * 1024 * 1024);      // 64 KB
    float* esq    = qsq + M_TOTAL;                                   // 32 KB
    unsigned* k1s = (unsigned*)(ws + (size_t)13 * 1024 * 1024);      // 4 MB
    unsigned* k2s = (unsigned*)(ws + (size_t)17 * 1024 * 1024);      // 4 MB
    int*   fcount = (int*)     (ws + (size_t)25 * 1024 * 1024);      // 4 B
    int*   flist  = fcount + 64;                                     // 64 KB
    // refine partials alias k1s/k2s (finalize consumed them; stream-ordered)
    float* rp_v   = (float*)k1s;
    int*   rp_i   = (int*)k2s;

    hipMemsetAsync(out + M_TOTAL + (size_t)M_TOTAL * KDIM, 0, sizeof(float), stream);
    hipMemsetAsync(fcount, 0, sizeof(int), stream);

    prep_kernel<<<M_TOTAL / 4, 256, 0, stream>>>(Q, Qh, qsq, SQ_SCALE);
    prep_kernel<<<N_CODES / 4, 256, 0, stream>>>(E, Eh, esq, SE_SCALE);

    mfma_top2_kernel<<<dim3(M_TOTAL / BM, N_CODES / BN), 256, 0, stream>>>(
        Qh, Eh, esq, k1s, k2s);

    finalize_kernel<<<M_TOTAL / 4, 256, 0, stream>>>(Q, E, k1s, k2s, fcount, flist, out);
    refine_partial_kernel<<<RP_BLOCKS, 256, 0, stream>>>(Q, E, qsq, esq, fcount, flist, rp_v, rp_i);
    refine_merge_kernel<<<RM_BLOCKS, 64, 0, stream>>>(Q, E, fcount, flist, rp_v, rp_i, out);
}